// Round 1
// baseline (8098.096 us; speedup 1.0000x reference)
//
#include <hip/hip_runtime.h>
#include <hip/hip_bf16.h>

// RNN: outs[t] = h_t = tanh(x[t]@Wx + b + h_{t-1}@Wh), T=512,B=64,IN=512,H=1024
// Strategy:
//  - split-bf16 (hi+lo) MFMA everywhere (no fp32 MFMA on CDNA4); 3-term product
//  - phase A: xw = x@Wx+b written directly into d_out (it's overwritten by h_t in place)
//  - scan: 128 persistent wgs = 4 batch-groups(16 rows) x 32 col-groups(32 cols),
//    Wh fragments REGISTER-resident across all 512 steps (K split over 4 waves),
//    flag sub-barrier per batch-group per step, h ping-pong as bf16 hi/lo in ws.

#define T_ 512
#define B_ 64
#define IN_ 512
#define H_ 1024
constexpr int TBH = T_ * B_ * H_;   // 33,554,432
constexpr int HB  = B_ * H_;        // 65,536

typedef unsigned short u16;
typedef __attribute__((ext_vector_type(8))) short short8;   // 8 x bf16 (4 VGPRs)
typedef __attribute__((ext_vector_type(4))) float f32x4;

__device__ __forceinline__ void splitbf(float x, u16& hi, u16& lo) {
    unsigned u = __float_as_uint(x);
    hi = (u16)(u >> 16);                       // truncated bf16 hi
    float r = x - __uint_as_float(u & 0xffff0000u);
    lo = (u16)(__float_as_uint(r) >> 16);      // bf16 of residual; total rel err ~2^-16
}

// ---- prep kernels ------------------------------------------------------------
__global__ void k_split4(const float4* __restrict__ in, u16* __restrict__ hi,
                         u16* __restrict__ lo, int n4) {
    int i = blockIdx.x * blockDim.x + threadIdx.x;
    int stride = gridDim.x * blockDim.x;
    for (; i < n4; i += stride) {
        float4 v = in[i];
        u16 h0,h1,h2,h3,l0,l1,l2,l3;
        splitbf(v.x,h0,l0); splitbf(v.y,h1,l1); splitbf(v.z,h2,l2); splitbf(v.w,h3,l3);
        uint2 hv, lv;
        hv.x = (unsigned)h0 | ((unsigned)h1 << 16);
        hv.y = (unsigned)h2 | ((unsigned)h3 << 16);
        lv.x = (unsigned)l0 | ((unsigned)l1 << 16);
        lv.y = (unsigned)l2 | ((unsigned)l3 << 16);
        *(uint2*)&hi[4*i] = hv;
        *(uint2*)&lo[4*i] = lv;
    }
}

// src [K][N] fp32 -> dst [N][K] bf16 hi/lo (transposed for B-fragment reads)
__global__ void k_tsplit(const float* __restrict__ src, u16* __restrict__ hi,
                         u16* __restrict__ lo, int K, int N) {
    int id = blockIdx.x * 256 + threadIdx.x;
    if (id >= K * N) return;
    int k = id / N, n = id % N;
    u16 h, l; splitbf(src[id], h, l);
    hi[n*K + k] = h; lo[n*K + k] = l;
}

// h0 fp32 -> hbuf buffer 1 (read at t=0)
__global__ void k_h0(const float* __restrict__ h0, u16* __restrict__ hbuf) {
    int id = blockIdx.x * 256 + threadIdx.x;
    if (id >= HB) return;
    u16 h, l; splitbf(h0[id], h, l);
    hbuf[2*HB + id] = h;   // [buf=1][hi]
    hbuf[3*HB + id] = l;   // [buf=1][lo]
}

// ---- phase A: xw = x@Wx + b, split-bf16 MFMA, 128x128 tile, frags from global -
__launch_bounds__(256, 2)
__global__ void k_gemm_xw(const u16* __restrict__ xhi, const u16* __restrict__ xlo,
                          const u16* __restrict__ wthi, const u16* __restrict__ wtlo,
                          const float* __restrict__ bias, float* __restrict__ out) {
    int bid = blockIdx.x;
    int mi = bid >> 3, ni = bid & 7;
    int m0 = mi * 128, n0 = ni * 128;
    int wave = threadIdx.x >> 6, lane = threadIdx.x & 63;
    int wr = wave >> 1, wc = wave & 1;
    int lrow = lane & 15, lk8 = (lane >> 4) * 8;
    const int rowb = m0 + wr*64 + lrow;   // A row for this lane
    const int colb = n0 + wc*64 + lrow;   // B col for this lane
    f32x4 acc[4][4] = {};
    for (int kt = 0; kt < 16; ++kt) {
        int kb = kt*32 + lk8;
        short8 ah[4], al[4], bh[4], bl[4];
#pragma unroll
        for (int mt = 0; mt < 4; ++mt) {
            ah[mt] = *(const short8*)&xhi[(size_t)(rowb + mt*16)*IN_ + kb];
            al[mt] = *(const short8*)&xlo[(size_t)(rowb + mt*16)*IN_ + kb];
        }
#pragma unroll
        for (int nt = 0; nt < 4; ++nt) {
            bh[nt] = *(const short8*)&wthi[(size_t)(colb + nt*16)*IN_ + kb];
            bl[nt] = *(const short8*)&wtlo[(size_t)(colb + nt*16)*IN_ + kb];
        }
#pragma unroll
        for (int mt = 0; mt < 4; ++mt)
#pragma unroll
            for (int nt = 0; nt < 4; ++nt) {
                acc[mt][nt] = __builtin_amdgcn_mfma_f32_16x16x32_bf16(ah[mt], bh[nt], acc[mt][nt], 0,0,0);
                acc[mt][nt] = __builtin_amdgcn_mfma_f32_16x16x32_bf16(ah[mt], bl[nt], acc[mt][nt], 0,0,0);
                acc[mt][nt] = __builtin_amdgcn_mfma_f32_16x16x32_bf16(al[mt], bh[nt], acc[mt][nt], 0,0,0);
            }
    }
    // epilogue: D layout col=lane&15, row=4*(lane>>4)+reg
    int orow0 = m0 + wr*64 + 4*(lane >> 4);
#pragma unroll
    for (int nt = 0; nt < 4; ++nt) {
        int col = n0 + wc*64 + nt*16 + (lane & 15);
        float bv = bias[col];
#pragma unroll
        for (int mt = 0; mt < 4; ++mt)
#pragma unroll
            for (int r = 0; r < 4; ++r)
                out[(size_t)(orow0 + mt*16 + r)*H_ + col] = acc[mt][nt][r] + bv;
    }
}

// ---- phase A fallback (fp32 vector) if ws too small for split buffers --------
__global__ void k_gemm_f32(const float* __restrict__ A, const float* __restrict__ Bw,
                           const float* __restrict__ bias, float* __restrict__ out) {
    __shared__ float As[32][65];  // [k][m]
    __shared__ float Bs[32][65];  // [k][n]
    int n0 = blockIdx.x * 64, m0 = blockIdx.y * 64;
    int tid = threadIdx.x;
    int tr = tid >> 4, tc = tid & 15;
    float acc[4][4] = {};
    for (int kc = 0; kc < IN_; kc += 32) {
#pragma unroll
        for (int it = 0; it < 8; ++it) {
            int id = tid + 256*it;
            int k = id & 31, m = id >> 5;
            As[k][m] = A[(size_t)(m0 + m)*IN_ + kc + k];
        }
#pragma unroll
        for (int it = 0; it < 8; ++it) {
            int id = tid + 256*it;
            int n = id & 63, kk = id >> 6;
            Bs[kk][n] = Bw[(size_t)(kc + kk)*H_ + n0 + n];
        }
        __syncthreads();
#pragma unroll
        for (int kk = 0; kk < 32; ++kk) {
            float a[4], b[4];
#pragma unroll
            for (int i = 0; i < 4; ++i) a[i] = As[kk][tr*4+i];
#pragma unroll
            for (int j = 0; j < 4; ++j) b[j] = Bs[kk][tc*4+j];
#pragma unroll
            for (int i = 0; i < 4; ++i)
#pragma unroll
                for (int j = 0; j < 4; ++j) acc[i][j] += a[i]*b[j];
        }
        __syncthreads();
    }
#pragma unroll
    for (int i = 0; i < 4; ++i)
#pragma unroll
        for (int j = 0; j < 4; ++j)
            out[(size_t)(m0 + tr*4 + i)*H_ + n0 + tc*4 + j] = acc[i][j] + bias[n0 + tc*4 + j];
}

// ---- scan: persistent, Wh register-resident, flag sub-barriers ---------------
__launch_bounds__(256, 1)
__global__ void k_scan(const float* __restrict__ wh,   // [H][H] fp32 (k-major)
                       float* __restrict__ out,        // [T][B][H] xw in / h out, + tail h_last
                       u16* __restrict__ hbuf,         // [2 buf][2 hl][B][H] bf16
                       int* __restrict__ flags) {      // [4 groups][T]
    const int NCOL = 32;
    int bid = blockIdx.x;
    int g = bid >> 5, cg = bid & 31;
    int n0 = cg * 32;
    int row_g = g * 16;
    int wave = threadIdx.x >> 6, lane = threadIdx.x & 63;
    int lrow = lane & 15, lk8 = (lane >> 4) * 8;
    __shared__ float partial[4 * 16 * 33];   // [wave][row][col(+pad)]

    // Load Wh fragments ONCE into registers: this wave covers k in [wave*256, wave*256+256)
    short8 bh[2][8], bl[2][8];
#pragma unroll
    for (int nt = 0; nt < 2; ++nt) {
        int col = n0 + nt*16 + lrow;
#pragma unroll
        for (int kt = 0; kt < 8; ++kt) {
            int kbase = wave*256 + kt*32 + lk8;
            short8 h8, l8;
#pragma unroll
            for (int j = 0; j < 8; ++j) {
                u16 hh, ll; splitbf(wh[(size_t)(kbase + j)*H_ + col], hh, ll);
                h8[j] = (short)hh; l8[j] = (short)ll;
            }
            bh[nt][kt] = h8; bl[nt][kt] = l8;
        }
    }

    for (int t = 0; t < T_; ++t) {
        const u16* hHi = hbuf + (size_t)(((t+1)&1)*2 + 0)*HB;   // h_{t-1}
        const u16* hLo = hbuf + (size_t)(((t+1)&1)*2 + 1)*HB;
        u16* nHi = hbuf + (size_t)((t&1)*2 + 0)*HB;             // h_t
        u16* nLo = hbuf + (size_t)((t&1)*2 + 1)*HB;

        // prefetch xw (independent of h)
        float xwv[2];
#pragma unroll
        for (int e = 0; e < 2; ++e) {
            int idx = threadIdx.x + 256*e;
            xwv[e] = out[(size_t)(t*B_ + row_g + (idx >> 5))*H_ + n0 + (idx & 31)];
        }

        f32x4 acc[2] = {};
#pragma unroll
        for (int kt = 0; kt < 8; ++kt) {
            int kbase = wave*256 + kt*32 + lk8;
            short8 ah = *(const short8*)&hHi[(size_t)(row_g + lrow)*H_ + kbase];
            short8 al = *(const short8*)&hLo[(size_t)(row_g + lrow)*H_ + kbase];
#pragma unroll
            for (int nt = 0; nt < 2; ++nt) {
                acc[nt] = __builtin_amdgcn_mfma_f32_16x16x32_bf16(ah, bh[nt][kt], acc[nt], 0,0,0);
                acc[nt] = __builtin_amdgcn_mfma_f32_16x16x32_bf16(ah, bl[nt][kt], acc[nt], 0,0,0);
                acc[nt] = __builtin_amdgcn_mfma_f32_16x16x32_bf16(al, bh[nt][kt], acc[nt], 0,0,0);
            }
        }
        // K-partials to LDS: [wave][row][col], row=4*(lane>>4)+r, col=nt*16+lrow
        {
            int r0 = 4 * (lane >> 4);
#pragma unroll
            for (int nt = 0; nt < 2; ++nt) {
                int c = nt*16 + lrow;
#pragma unroll
                for (int r = 0; r < 4; ++r)
                    partial[(wave*16 + r0 + r)*33 + c] = acc[nt][r];
            }
        }
        __syncthreads();
        // reduce 4 K-partials + xw, tanh, write h
#pragma unroll
        for (int e = 0; e < 2; ++e) {
            int idx = threadIdx.x + 256*e;
            int r = idx >> 5, c = idx & 31;
            float s = xwv[e];
#pragma unroll
            for (int w = 0; w < 4; ++w) s += partial[(w*16 + r)*33 + c];
            float y = tanhf(s);
            int gb = row_g + r;
            out[(size_t)(t*B_ + gb)*H_ + n0 + c] = y;
            u16 hh, ll; splitbf(y, hh, ll);
            nHi[(size_t)gb*H_ + n0 + c] = hh;
            nLo[(size_t)gb*H_ + n0 + c] = ll;
            if (t == T_-1) out[(size_t)TBH + (size_t)gb*H_ + n0 + c] = y;  // h_last tail
        }
        __syncthreads();   // LDS reads done + this wg's h stores issued
        if (threadIdx.x == 0) {
            __threadfence();                                   // release (cross-XCD)
            atomicAdd(&flags[g*T_ + t], 1);
            while (__hip_atomic_load(&flags[g*T_ + t], __ATOMIC_RELAXED,
                                     __HIP_MEMORY_SCOPE_AGENT) < NCOL)
                __builtin_amdgcn_s_sleep(1);
        }
        __syncthreads();
        __threadfence();   // acquire: invalidate stale L1/L2 before reading peers' h
    }
}

// ---- host --------------------------------------------------------------------
extern "C" void kernel_launch(void* const* d_in, const int* in_sizes, int n_in,
                              void* d_out, int out_size, void* d_ws, size_t ws_size,
                              hipStream_t stream) {
    const float* x    = (const float*)d_in[0];
    const float* h0   = (const float*)d_in[1];
    const float* Wx   = (const float*)d_in[2];
    const float* Wh   = (const float*)d_in[3];
    const float* bias = (const float*)d_in[4];
    float* out = (float*)d_out;

    const size_t nX = (size_t)T_ * B_ * IN_;            // 16,777,216
    const size_t nWx = (size_t)IN_ * H_;                // 524,288
    const size_t hbufB = (size_t)4 * HB * sizeof(u16);  // 512 KB
    const size_t flagB = (size_t)4 * T_ * sizeof(int);  // 8 KB
    const size_t FULL_NEED = 2*nX*2 + 2*nWx*2 + hbufB + flagB;   // ~66.5 MiB
    const size_t SAFE_NEED = hbufB + flagB;
    if (ws_size < SAFE_NEED) return;   // cannot run; fail loudly

    bool full = ws_size >= FULL_NEED;
    u16 *xhi, *xlo, *wthi, *wtlo, *hbuf;
    if (full) {
        xhi  = (u16*)d_ws;
        xlo  = xhi + nX;
        wthi = xlo + nX;
        wtlo = wthi + nWx;
        hbuf = wtlo + nWx;
    } else {
        hbuf = (u16*)d_ws;
    }
    int* flags = (int*)(hbuf + 4*HB);

    hipMemsetAsync(flags, 0, flagB, stream);
    k_h0<<<HB/256, 256, 0, stream>>>(h0, hbuf);
    if (full) {
        k_split4<<<2048, 256, 0, stream>>>((const float4*)x, xhi, xlo, (int)(nX/4));
        k_tsplit<<<(int)(nWx/256), 256, 0, stream>>>(Wx, wthi, wtlo, IN_, H_);
        k_gemm_xw<<<2048, 256, 0, stream>>>(xhi, xlo, wthi, wtlo, bias, out);
    } else {
        k_gemm_f32<<<dim3(16, 512), 256, 0, stream>>>(x, Wx, bias, out);
    }
    k_scan<<<128, 256, 0, stream>>>(Wh, out, hbuf, flags);
}

// Round 2
// 5092.038 us; speedup vs baseline: 1.5903x; 1.5903x over previous
//
#include <hip/hip_runtime.h>
#include <hip/hip_bf16.h>

// RNN: outs[t] = h_t = tanh(x[t]@Wx + b + h_{t-1}@Wh), T=512,B=64,IN=512,H=1024
// Strategy:
//  - split-bf16 (hi+lo) MFMA everywhere (no fp32 MFMA on CDNA4); 3-term product
//  - phase A: xw = x@Wx+b written directly into d_out (overwritten by h_t in place)
//  - scan: 128 persistent wgs = 4 batch-groups(16 rows) x 32 col-groups(32 cols),
//    Wh fragments REGISTER-resident across all 512 steps (K split over 4 waves),
//    flag sub-barrier per batch-group per step, h ping-pong as bf16 hi/lo in ws.
//  - R1: NO fences in the scan loop. Only h traffic is device-coherent
//    (relaxed AGENT atomic load/store = sc-flagged, bypasses stale L1/L2);
//    barrier is release-RMW + relaxed polls. Avoids per-step buffer_inv L2 wipe
//    (was 15.5 us/step, FETCH 4.4x over-stream).

#define T_ 512
#define B_ 64
#define IN_ 512
#define H_ 1024
constexpr int TBH = T_ * B_ * H_;   // 33,554,432
constexpr int HB  = B_ * H_;        // 65,536

typedef unsigned short u16;
typedef unsigned long long u64;
typedef __attribute__((ext_vector_type(8))) short short8;   // 8 x bf16 (4 VGPRs)
typedef __attribute__((ext_vector_type(4))) float f32x4;

__device__ __forceinline__ void splitbf(float x, u16& hi, u16& lo) {
    unsigned u = __float_as_uint(x);
    hi = (u16)(u >> 16);                       // truncated bf16 hi
    float r = x - __uint_as_float(u & 0xffff0000u);
    lo = (u16)(__float_as_uint(r) >> 16);      // bf16 of residual; total rel err ~2^-16
}

// device-coherent load of 8 bf16 (two 8B agent-scope loads; bypass stale L1/L2)
__device__ __forceinline__ short8 load8_coh(const u16* p) {
    u64 a = __hip_atomic_load((const u64*)p,     __ATOMIC_RELAXED, __HIP_MEMORY_SCOPE_AGENT);
    u64 b = __hip_atomic_load((const u64*)p + 1, __ATOMIC_RELAXED, __HIP_MEMORY_SCOPE_AGENT);
    union { u64 q[2]; short8 v; } u;
    u.q[0] = a; u.q[1] = b;
    return u.v;
}

__device__ __forceinline__ void store4_coh(u16* p, unsigned v) {
    __hip_atomic_store((unsigned*)p, v, __ATOMIC_RELAXED, __HIP_MEMORY_SCOPE_AGENT);
}

// ---- prep kernels ------------------------------------------------------------
__global__ void k_split4(const float4* __restrict__ in, u16* __restrict__ hi,
                         u16* __restrict__ lo, int n4) {
    int i = blockIdx.x * blockDim.x + threadIdx.x;
    int stride = gridDim.x * blockDim.x;
    for (; i < n4; i += stride) {
        float4 v = in[i];
        u16 h0,h1,h2,h3,l0,l1,l2,l3;
        splitbf(v.x,h0,l0); splitbf(v.y,h1,l1); splitbf(v.z,h2,l2); splitbf(v.w,h3,l3);
        uint2 hv, lv;
        hv.x = (unsigned)h0 | ((unsigned)h1 << 16);
        hv.y = (unsigned)h2 | ((unsigned)h3 << 16);
        lv.x = (unsigned)l0 | ((unsigned)l1 << 16);
        lv.y = (unsigned)l2 | ((unsigned)l3 << 16);
        *(uint2*)&hi[4*i] = hv;
        *(uint2*)&lo[4*i] = lv;
    }
}

// src [K][N] fp32 -> dst [N][K] bf16 hi/lo (transposed for B-fragment reads)
__global__ void k_tsplit(const float* __restrict__ src, u16* __restrict__ hi,
                         u16* __restrict__ lo, int K, int N) {
    int id = blockIdx.x * 256 + threadIdx.x;
    if (id >= K * N) return;
    int k = id / N, n = id % N;
    u16 h, l; splitbf(src[id], h, l);
    hi[n*K + k] = h; lo[n*K + k] = l;
}

// h0 fp32 -> hbuf buffer 1 (read at t=0)
__global__ void k_h0(const float* __restrict__ h0, u16* __restrict__ hbuf) {
    int id = blockIdx.x * 256 + threadIdx.x;
    if (id >= HB) return;
    u16 h, l; splitbf(h0[id], h, l);
    hbuf[2*HB + id] = h;   // [buf=1][hi]
    hbuf[3*HB + id] = l;   // [buf=1][lo]
}

// ---- phase A: xw = x@Wx + b, split-bf16 MFMA, 128x128 tile, frags from global -
__launch_bounds__(256, 2)
__global__ void k_gemm_xw(const u16* __restrict__ xhi, const u16* __restrict__ xlo,
                          const u16* __restrict__ wthi, const u16* __restrict__ wtlo,
                          const float* __restrict__ bias, float* __restrict__ out) {
    int bid = blockIdx.x;
    int mi = bid >> 3, ni = bid & 7;
    int m0 = mi * 128, n0 = ni * 128;
    int wave = threadIdx.x >> 6, lane = threadIdx.x & 63;
    int wr = wave >> 1, wc = wave & 1;
    int lrow = lane & 15, lk8 = (lane >> 4) * 8;
    const int rowb = m0 + wr*64 + lrow;   // A row for this lane
    const int colb = n0 + wc*64 + lrow;   // B col for this lane
    f32x4 acc[4][4] = {};
    for (int kt = 0; kt < 16; ++kt) {
        int kb = kt*32 + lk8;
        short8 ah[4], al[4], bh[4], bl[4];
#pragma unroll
        for (int mt = 0; mt < 4; ++mt) {
            ah[mt] = *(const short8*)&xhi[(size_t)(rowb + mt*16)*IN_ + kb];
            al[mt] = *(const short8*)&xlo[(size_t)(rowb + mt*16)*IN_ + kb];
        }
#pragma unroll
        for (int nt = 0; nt < 4; ++nt) {
            bh[nt] = *(const short8*)&wthi[(size_t)(colb + nt*16)*IN_ + kb];
            bl[nt] = *(const short8*)&wtlo[(size_t)(colb + nt*16)*IN_ + kb];
        }
#pragma unroll
        for (int mt = 0; mt < 4; ++mt)
#pragma unroll
            for (int nt = 0; nt < 4; ++nt) {
                acc[mt][nt] = __builtin_amdgcn_mfma_f32_16x16x32_bf16(ah[mt], bh[nt], acc[mt][nt], 0,0,0);
                acc[mt][nt] = __builtin_amdgcn_mfma_f32_16x16x32_bf16(ah[mt], bl[nt], acc[mt][nt], 0,0,0);
                acc[mt][nt] = __builtin_amdgcn_mfma_f32_16x16x32_bf16(al[mt], bh[nt], acc[mt][nt], 0,0,0);
            }
    }
    // epilogue: D layout col=lane&15, row=4*(lane>>4)+reg
    int orow0 = m0 + wr*64 + 4*(lane >> 4);
#pragma unroll
    for (int nt = 0; nt < 4; ++nt) {
        int col = n0 + wc*64 + nt*16 + (lane & 15);
        float bv = bias[col];
#pragma unroll
        for (int mt = 0; mt < 4; ++mt)
#pragma unroll
            for (int r = 0; r < 4; ++r)
                out[(size_t)(orow0 + mt*16 + r)*H_ + col] = acc[mt][nt][r] + bv;
    }
}

// ---- phase A fallback (fp32 vector) if ws too small for split buffers --------
__global__ void k_gemm_f32(const float* __restrict__ A, const float* __restrict__ Bw,
                           const float* __restrict__ bias, float* __restrict__ out) {
    __shared__ float As[32][65];  // [k][m]
    __shared__ float Bs[32][65];  // [k][n]
    int n0 = blockIdx.x * 64, m0 = blockIdx.y * 64;
    int tid = threadIdx.x;
    int tr = tid >> 4, tc = tid & 15;
    float acc[4][4] = {};
    for (int kc = 0; kc < IN_; kc += 32) {
#pragma unroll
        for (int it = 0; it < 8; ++it) {
            int id = tid + 256*it;
            int k = id & 31, m = id >> 5;
            As[k][m] = A[(size_t)(m0 + m)*IN_ + kc + k];
        }
#pragma unroll
        for (int it = 0; it < 8; ++it) {
            int id = tid + 256*it;
            int n = id & 63, kk = id >> 6;
            Bs[kk][n] = Bw[(size_t)(kc + kk)*H_ + n0 + n];
        }
        __syncthreads();
#pragma unroll
        for (int kk = 0; kk < 32; ++kk) {
            float a[4], b[4];
#pragma unroll
            for (int i = 0; i < 4; ++i) a[i] = As[kk][tr*4+i];
#pragma unroll
            for (int j = 0; j < 4; ++j) b[j] = Bs[kk][tc*4+j];
#pragma unroll
            for (int i = 0; i < 4; ++i)
#pragma unroll
                for (int j = 0; j < 4; ++j) acc[i][j] += a[i]*b[j];
        }
        __syncthreads();
    }
#pragma unroll
    for (int i = 0; i < 4; ++i)
#pragma unroll
        for (int j = 0; j < 4; ++j)
            out[(size_t)(m0 + tr*4 + i)*H_ + n0 + tc*4 + j] = acc[i][j] + bias[n0 + tc*4 + j];
}

// ---- scan: persistent, Wh register-resident, fence-free coherent h exchange --
__launch_bounds__(256, 1)
__global__ void k_scan(const float* __restrict__ wh,   // [H][H] fp32 (k-major)
                       float* __restrict__ out,        // [T][B][H] xw in / h out, + tail h_last
                       u16* __restrict__ hbuf,         // [2 buf][2 hl][B][H] bf16
                       int* __restrict__ flags) {      // [4 groups][T]
    const int NCOL = 32;
    int bid = blockIdx.x;
    int g = bid >> 5, cg = bid & 31;
    int n0 = cg * 32;
    int row_g = g * 16;
    int wave = threadIdx.x >> 6, lane = threadIdx.x & 63;
    int lrow = lane & 15, lk8 = (lane >> 4) * 8;
    __shared__ float partial[4 * 16 * 33];   // [wave][row][col(+pad)]

    // Load Wh fragments ONCE into registers: this wave covers k in [wave*256, wave*256+256)
    short8 bh[2][8], bl[2][8];
#pragma unroll
    for (int nt = 0; nt < 2; ++nt) {
        int col = n0 + nt*16 + lrow;
#pragma unroll
        for (int kt = 0; kt < 8; ++kt) {
            int kbase = wave*256 + kt*32 + lk8;
            short8 h8, l8;
#pragma unroll
            for (int j = 0; j < 8; ++j) {
                u16 hh, ll; splitbf(wh[(size_t)(kbase + j)*H_ + col], hh, ll);
                h8[j] = (short)hh; l8[j] = (short)ll;
            }
            bh[nt][kt] = h8; bl[nt][kt] = l8;
        }
    }

    // epilogue indexing: row r, col-pair cp (2 adjacent cols)
    const int er = threadIdx.x >> 4;         // 0..15
    const int ec0 = (threadIdx.x & 15) * 2;  // 0,2,..,30

    for (int t = 0; t < T_; ++t) {
        const u16* hHi = hbuf + (size_t)(((t+1)&1)*2 + 0)*HB;   // h_{t-1}
        const u16* hLo = hbuf + (size_t)(((t+1)&1)*2 + 1)*HB;
        u16* nHi = hbuf + (size_t)((t&1)*2 + 0)*HB;             // h_t
        u16* nLo = hbuf + (size_t)((t&1)*2 + 1)*HB;

        // issue ALL coherent h loads first (overlap latency)
        short8 ah[8], al[8];
#pragma unroll
        for (int kt = 0; kt < 8; ++kt) {
            int kbase = wave*256 + kt*32 + lk8;
            const size_t off = (size_t)(row_g + lrow)*H_ + kbase;
            ah[kt] = load8_coh(&hHi[off]);
            al[kt] = load8_coh(&hLo[off]);
        }
        // xw prefetch (plain cached loads; region private to this wg)
        float2 xwv = *(const float2*)&out[(size_t)(t*B_ + row_g + er)*H_ + n0 + ec0];

        f32x4 acc[2] = {};
#pragma unroll
        for (int kt = 0; kt < 8; ++kt) {
#pragma unroll
            for (int nt = 0; nt < 2; ++nt) {
                acc[nt] = __builtin_amdgcn_mfma_f32_16x16x32_bf16(ah[kt], bh[nt][kt], acc[nt], 0,0,0);
                acc[nt] = __builtin_amdgcn_mfma_f32_16x16x32_bf16(ah[kt], bl[nt][kt], acc[nt], 0,0,0);
                acc[nt] = __builtin_amdgcn_mfma_f32_16x16x32_bf16(al[kt], bh[nt][kt], acc[nt], 0,0,0);
            }
        }
        // K-partials to LDS: [wave][row][col], row=4*(lane>>4)+r, col=nt*16+lrow
        {
            int r0 = 4 * (lane >> 4);
#pragma unroll
            for (int nt = 0; nt < 2; ++nt) {
                int c = nt*16 + lrow;
#pragma unroll
                for (int r = 0; r < 4; ++r)
                    partial[(wave*16 + r0 + r)*33 + c] = acc[nt][r];
            }
        }
        __syncthreads();
        // reduce 4 K-partials + xw, tanh, write h (coherent) + out (plain)
        {
            float s0 = xwv.x, s1 = xwv.y;
#pragma unroll
            for (int w = 0; w < 4; ++w) {
                s0 += partial[(w*16 + er)*33 + ec0];
                s1 += partial[(w*16 + er)*33 + ec0 + 1];
            }
            float y0 = tanhf(s0), y1 = tanhf(s1);
            int gb = row_g + er;
            *(float2*)&out[(size_t)(t*B_ + gb)*H_ + n0 + ec0] = make_float2(y0, y1);
            u16 h0,l0,h1,l1;
            splitbf(y0,h0,l0); splitbf(y1,h1,l1);
            store4_coh(&nHi[(size_t)gb*H_ + n0 + ec0], (unsigned)h0 | ((unsigned)h1 << 16));
            store4_coh(&nLo[(size_t)gb*H_ + n0 + ec0], (unsigned)l0 | ((unsigned)l1 << 16));
            if (t == T_-1)
                *(float2*)&out[(size_t)TBH + (size_t)gb*H_ + n0 + ec0] = make_float2(y0, y1);
        }
        __syncthreads();   // all lanes done with LDS + h stores issued
        if (threadIdx.x == 0) {
            // release RMW: waitcnt drains our coherent h stores; NO cache invalidate
            __hip_atomic_fetch_add(&flags[g*T_ + t], 1, __ATOMIC_RELEASE,
                                   __HIP_MEMORY_SCOPE_AGENT);
            while (__hip_atomic_load(&flags[g*T_ + t], __ATOMIC_RELAXED,
                                     __HIP_MEMORY_SCOPE_AGENT) < NCOL)
                __builtin_amdgcn_s_sleep(1);
        }
        __syncthreads();
        // no fence: next iteration's h loads are themselves device-coherent
    }
}

// ---- host --------------------------------------------------------------------
extern "C" void kernel_launch(void* const* d_in, const int* in_sizes, int n_in,
                              void* d_out, int out_size, void* d_ws, size_t ws_size,
                              hipStream_t stream) {
    const float* x    = (const float*)d_in[0];
    const float* h0   = (const float*)d_in[1];
    const float* Wx   = (const float*)d_in[2];
    const float* Wh   = (const float*)d_in[3];
    const float* bias = (const float*)d_in[4];
    float* out = (float*)d_out;

    const size_t nX = (size_t)T_ * B_ * IN_;            // 16,777,216
    const size_t nWx = (size_t)IN_ * H_;                // 524,288
    const size_t hbufB = (size_t)4 * HB * sizeof(u16);  // 512 KB
    const size_t flagB = (size_t)4 * T_ * sizeof(int);  // 8 KB
    const size_t FULL_NEED = 2*nX*2 + 2*nWx*2 + hbufB + flagB;   // ~66.5 MiB
    const size_t SAFE_NEED = hbufB + flagB;
    if (ws_size < SAFE_NEED) return;   // cannot run; fail loudly

    bool full = ws_size >= FULL_NEED;
    u16 *xhi, *xlo, *wthi, *wtlo, *hbuf;
    if (full) {
        xhi  = (u16*)d_ws;
        xlo  = xhi + nX;
        wthi = xlo + nX;
        wtlo = wthi + nWx;
        hbuf = wtlo + nWx;
    } else {
        hbuf = (u16*)d_ws;
    }
    int* flags = (int*)(hbuf + 4*HB);

    hipMemsetAsync(flags, 0, flagB, stream);
    k_h0<<<HB/256, 256, 0, stream>>>(h0, hbuf);
    if (full) {
        k_split4<<<2048, 256, 0, stream>>>((const float4*)x, xhi, xlo, (int)(nX/4));
        k_tsplit<<<(int)(nWx/256), 256, 0, stream>>>(Wx, wthi, wtlo, IN_, H_);
        k_gemm_xw<<<2048, 256, 0, stream>>>(xhi, xlo, wthi, wtlo, bias, out);
    } else {
        k_gemm_f32<<<dim3(16, 512), 256, 0, stream>>>(x, Wx, bias, out);
    }
    k_scan<<<128, 256, 0, stream>>>(Wh, out, hbuf, flags);
}